// Round 6
// baseline (816.080 us; speedup 1.0000x reference)
//
#include <hip/hip_runtime.h>
#include <hip/hip_cooperative_groups.h>
#include <math.h>

namespace cg = cooperative_groups;

#define MDIM 24
#define ZDIM 1024
#define NBLK 1024
#define NTHR 256
#define NEG_INF_F -1e30f
#define EPS_F 1e-12f
#define NCH3 64          // i-chunks per sector in phase3 (16 i's each)

// ws layout (float offsets)
enum {
  OFF_PC   = 0,          // lamda*(price+h)      [24][1024]
  OFF_CC   = 24576,      // slog(A) - beta*pc    [24][1024]
  OFF_U    = 49152,      // U_ni                 [24][1024]
  OFF_RMAX = 73728,      // loc-logit max        [24][1024]
  OFF_SEXP = 98304,      // loc sumexp           [24][1024]
  OFF_D    = 122880,     // D_ni                 [24][1024]
  OFF_XP   = 147456,     // X_pred               [24][1024]
  OFF_PART = 172032,     // per-block loss partials [1024]
  OFF_LOC  = 173056      // int loc[24]
};

// ---- mask handling: bool masks may arrive as packed bytes or 32-bit words.
__device__ __forceinline__ bool masks_are_bytes(const void* hm, const void* gm) {
  const unsigned int* hw = (const unsigned int*)hm;
  const unsigned int* gw = (const unsigned int*)gm;
  bool b = false;
  #pragma unroll
  for (int k = 0; k < 6; k++) {   // first 24 bytes of each — safe in all layouts
    unsigned int a = hw[k], c = gw[k];
    if (a != 0u && a != 1u && a != 0x3F800000u) b = true;
    if (c != 0u && c != 1u && c != 0x3F800000u) b = true;
  }
  return b;
}
__device__ __forceinline__ bool loc_flag(const void* hm, const void* gm, int n) {
  bool bytes = masks_are_bytes(hm, gm);
  bool hv = bytes ? (((const unsigned char*)hm)[n] != 0)
                  : (((const unsigned int*)hm)[n] != 0u);
  bool gv = bytes ? (((const unsigned char*)gm)[n] != 0)
                  : (((const unsigned int*)gm)[n] != 0u);
  return gv && !hv;
}

// ============================ fused cooperative ==============================
__global__ __launch_bounds__(NTHR, 4) void fused(
    const float* __restrict__ t, const float* __restrict__ price,
    const float* __restrict__ h, const float* __restrict__ A_ni,
    const float* __restrict__ beta, const float* __restrict__ lamda,
    const float* __restrict__ demin, const float* __restrict__ demax,
    const float* __restrict__ delta, const float* __restrict__ omega,
    const float* __restrict__ sigma, const float* __restrict__ Kn,
    const float* __restrict__ attractor, const float* __restrict__ exogd,
    const float* __restrict__ X0, const float* __restrict__ exogp,
    const float* __restrict__ Xtg, const void* __restrict__ housing,
    const void* __restrict__ genflux, float* __restrict__ ws,
    float* __restrict__ out) {
  cg::grid_group grid = cg::this_grid();
  const int gid  = blockIdx.x * NTHR + threadIdx.x;
  const int lane = threadIdx.x & 63;

  // ---- phase 0: loc flags + pc/cc precompute --------------------------------
  if (gid < MDIM)
    ((int*)(ws + OFF_LOC))[gid] = loc_flag(housing, genflux, gid) ? 1 : 0;
  for (int e = gid; e < MDIM * ZDIM; e += NBLK * NTHR) {
    const int n = e >> 10;
    const float pc = lamda[n] * (price[e] + h[e]);
    const float sa = logf(fmaxf(A_ni[e], EPS_F));
    ws[OFF_PC + e] = pc;
    ws[OFF_CC + e] = sa - beta[n] * pc;
  }
  grid.sync();

  const int* loc = (const int*)(ws + OFF_LOC);

  // ---- phase 1: per-row location-softmax stats + U_ni -----------------------
  for (int e = gid; e < MDIM * ZDIM; e += NBLK * NTHR) {
    const int n = e >> 10;
    if (!loc[n]) {                       // Pr = eye  =>  U = pc + t[i,i]
      const int i = e & 1023;
      ws[OFF_U + e] = ws[OFF_PC + e] + t[(size_t)e * ZDIM + i];
    }
  }
  const int wv = blockIdx.x * 4 + (threadIdx.x >> 6);    // 0..4095
  for (int row = wv; row < MDIM * ZDIM; row += NBLK * 4) {
    const int n = row >> 10;
    if (!loc[n]) continue;
    const float bn = beta[n];
    const float4* t4  = (const float4*)(t + (size_t)row * ZDIM);
    const float4* pc4 = (const float4*)(ws + OFF_PC + n * ZDIM);
    const float4* cc4 = (const float4*)(ws + OFF_CC + n * ZDIM);
    float lg[16], uv[16];
    float mx = -INFINITY;
    #pragma unroll
    for (int k = 0; k < 4; k++) {
      const int f = lane + 64 * k;
      float4 tv = t4[f];
      float4 pv = pc4[f];
      float4 cv = cc4[f];
      uv[4*k+0] = pv.x + tv.x;  lg[4*k+0] = cv.x - bn * tv.x;
      uv[4*k+1] = pv.y + tv.y;  lg[4*k+1] = cv.y - bn * tv.y;
      uv[4*k+2] = pv.z + tv.z;  lg[4*k+2] = cv.z - bn * tv.z;
      uv[4*k+3] = pv.w + tv.w;  lg[4*k+3] = cv.w - bn * tv.w;
      mx = fmaxf(mx, fmaxf(fmaxf(lg[4*k], lg[4*k+1]), fmaxf(lg[4*k+2], lg[4*k+3])));
    }
    #pragma unroll
    for (int off = 32; off >= 1; off >>= 1)
      mx = fmaxf(mx, __shfl_xor(mx, off));
    float se = 0.f, su = 0.f;
    #pragma unroll
    for (int k = 0; k < 16; k++) {
      const float e = __expf(lg[k] - mx);
      se += e;
      su = fmaf(e, uv[k], su);
    }
    #pragma unroll
    for (int off = 32; off >= 1; off >>= 1) {
      se += __shfl_xor(se, off);
      su += __shfl_xor(su, off);
    }
    if (lane == 0) {
      ws[OFF_U + row]    = su / se;
      ws[OFF_RMAX + row] = mx;
      ws[OFF_SEXP + row] = se;
    }
  }
  grid.sync();

  // ---- phase 2: substitution softmax over n + total demand D_ni -------------
  {
    const int hw = blockIdx.x * 8 + (threadIdx.x >> 5);  // half-wave id = zone i
    const int n  = threadIdx.x & 31;
    if (hw < ZDIM) {
      const int i = hw;
      const bool nv = (n < MDIM);
      float Uv = 0.f, asl = NEG_INF_F;
      if (nv) {
        Uv  = ws[OFF_U + n * ZDIM + i];
        asl = logf(fmaxf(attractor[n * ZDIM + i], EPS_F));
      }
      float acc = 0.f;
      for (int m = 0; m < MDIM; m++) {
        const float Xt  = X0[m * ZDIM + i] + exogp[m * ZDIM + i];
        const float sig = sigma[m];
        float dm = 0.f, dd = 0.f, dl = 0.f, om = 0.f, kn = 0.f;
        if (nv) {
          dm = demin[m * MDIM + n];
          dd = demax[m * MDIM + n] - dm;
          dl = delta[m * MDIM + n];
          om = omega[m * MDIM + n];
          kn = Kn[m * MDIM + n];
        }
        const float a = dm + dd * __expf(-dl * Uv);
        const bool valid = nv && (kn > 0.f);
        const float l = valid ? asl - sig * om * a * Uv : NEG_INF_F;
        float mxl = l;
        #pragma unroll
        for (int off = 16; off >= 1; off >>= 1)
          mxl = fmaxf(mxl, __shfl_xor(mxl, off));   // within 32-lane half
        const float e = valid ? __expf(l - mxl) : 0.f;
        float se = e;
        #pragma unroll
        for (int off = 16; off >= 1; off >>= 1)
          se += __shfl_xor(se, off);
        const float S = (valid && se > 0.f) ? e / se : 1.0f;
        if (nv) acc = fmaf(a * S, Xt, acc);
      }
      if (nv) {
        const float Dv = exogd[n * ZDIM + i] + acc;
        ws[OFF_D + n * ZDIM + i]  = Dv;
        ws[OFF_XP + n * ZDIM + i] = loc[n] ? 0.f : Dv;   // eye-sector X_pred = D
      }
    }
  }
  grid.sync();

  // ---- phase 3: X_pred for loc sectors (second pass over t) -----------------
  for (int g = blockIdx.x; g < MDIM * NCH3; g += NBLK) {
    const int n = g >> 6, ic = g & (NCH3 - 1);
    if (!loc[n]) continue;
    const int tj = threadIdx.x;                          // float4 index over j
    const float bn = beta[n];
    const float4 cv = ((const float4*)(ws + OFF_CC + n * ZDIM))[tj];
    const float4* t4 = (const float4*)t;
    float x0 = 0.f, x1 = 0.f, x2 = 0.f, x3 = 0.f;
    for (int ii = 0; ii < ZDIM / NCH3; ii++) {
      const int i = ic * (ZDIM / NCH3) + ii;
      const int row = n * ZDIM + i;
      const float mx = ws[OFF_RMAX + row];
      const float w  = ws[OFF_D + row] / ws[OFF_SEXP + row];
      float4 tv = t4[(size_t)row * (ZDIM / 4) + tj];
      x0 = fmaf(w, __expf(cv.x - mx - bn * tv.x), x0);
      x1 = fmaf(w, __expf(cv.y - mx - bn * tv.y), x1);
      x2 = fmaf(w, __expf(cv.z - mx - bn * tv.z), x2);
      x3 = fmaf(w, __expf(cv.w - mx - bn * tv.w), x3);
    }
    float* xp = ws + OFF_XP + n * ZDIM + tj * 4;
    atomicAdd(xp + 0, x0);
    atomicAdd(xp + 1, x1);
    atomicAdd(xp + 2, x2);
    atomicAdd(xp + 3, x3);
  }
  grid.sync();

  // ---- phase 4: loss partials -----------------------------------------------
  {
    float s = 0.f;
    for (int e = gid; e < MDIM * ZDIM; e += NBLK * NTHR) {
      const float d = ws[OFF_XP + e] - Xtg[e];
      s = fmaf(d, d, s);
    }
    #pragma unroll
    for (int off = 32; off >= 1; off >>= 1) s += __shfl_xor(s, off);
    __shared__ float red[4];
    const int w = threadIdx.x >> 6;
    if (lane == 0) red[w] = s;
    __syncthreads();
    if (threadIdx.x == 0)
      ws[OFF_PART + blockIdx.x] = red[0] + red[1] + red[2] + red[3];
  }
  grid.sync();

  // ---- phase 5: final reduce (block 0) --------------------------------------
  if (blockIdx.x == 0) {
    float s = 0.f;
    for (int k = threadIdx.x; k < NBLK; k += NTHR) s += ws[OFF_PART + k];
    #pragma unroll
    for (int off = 32; off >= 1; off >>= 1) s += __shfl_xor(s, off);
    __shared__ float red2[4];
    const int w = threadIdx.x >> 6;
    if (lane == 0) red2[w] = s;
    __syncthreads();
    if (threadIdx.x == 0)
      *out = (red2[0] + red2[1] + red2[2] + red2[3]) * (1.0f / (MDIM * ZDIM));
  }
}

// ================= fallback pipeline (verified round-3 logic) ================
__global__ __launch_bounds__(256) void k1_rows(
    const float* __restrict__ t, const float* __restrict__ price,
    const float* __restrict__ h, const float* __restrict__ A_ni,
    const float* __restrict__ beta, const float* __restrict__ lamda,
    const void* __restrict__ housing, const void* __restrict__ genflux,
    float* __restrict__ ws) {
  const int n  = blockIdx.x >> 8;
  const int i0 = (blockIdx.x & 255) * 4;
  __shared__ float pc_s[ZDIM];
  __shared__ float cc_s[ZDIM];
  const float bn = beta[n], ln = lamda[n];
  for (int j = threadIdx.x; j < ZDIM; j += 256) {
    float pc = ln * (price[n * ZDIM + j] + h[n * ZDIM + j]);
    float sa = logf(fmaxf(A_ni[n * ZDIM + j], EPS_F));
    pc_s[j] = pc;
    cc_s[j] = sa - bn * pc;
  }
  __syncthreads();
  const int wave = threadIdx.x >> 6, lane = threadIdx.x & 63;
  const int i = i0 + wave;
  const int row = n * ZDIM + i;
  if (!loc_flag(housing, genflux, n)) {
    if (lane == 0)
      ws[OFF_U + row] = pc_s[i] + t[(size_t)row * ZDIM + i];
    return;
  }
  const float4* t4  = (const float4*)(t + (size_t)row * ZDIM);
  const float4* pc4 = (const float4*)pc_s;
  const float4* cc4 = (const float4*)cc_s;
  float lg[16], uv[16];
  float mx = -INFINITY;
  #pragma unroll
  for (int k = 0; k < 4; k++) {
    const int f = lane + 64 * k;
    float4 tv = t4[f];
    float4 pv = pc4[f];
    float4 cv = cc4[f];
    uv[4*k+0] = pv.x + tv.x;  lg[4*k+0] = cv.x - bn * tv.x;
    uv[4*k+1] = pv.y + tv.y;  lg[4*k+1] = cv.y - bn * tv.y;
    uv[4*k+2] = pv.z + tv.z;  lg[4*k+2] = cv.z - bn * tv.z;
    uv[4*k+3] = pv.w + tv.w;  lg[4*k+3] = cv.w - bn * tv.w;
    mx = fmaxf(mx, fmaxf(fmaxf(lg[4*k], lg[4*k+1]), fmaxf(lg[4*k+2], lg[4*k+3])));
  }
  #pragma unroll
  for (int off = 32; off >= 1; off >>= 1)
    mx = fmaxf(mx, __shfl_xor(mx, off));
  float se = 0.f, su = 0.f;
  #pragma unroll
  for (int k = 0; k < 16; k++) {
    float e = __expf(lg[k] - mx);
    se += e;
    su = fmaf(e, uv[k], su);
  }
  #pragma unroll
  for (int off = 32; off >= 1; off >>= 1) {
    se += __shfl_xor(se, off);
    su += __shfl_xor(su, off);
  }
  if (lane == 0) {
    ws[OFF_U + row]    = su / se;
    ws[OFF_RMAX + row] = mx;
    ws[OFF_SEXP + row] = se;
  }
}

__global__ __launch_bounds__(256) void k2_demand(
    const float* __restrict__ demin, const float* __restrict__ demax,
    const float* __restrict__ delta, const float* __restrict__ omega,
    const float* __restrict__ sigma, const float* __restrict__ Kn,
    const float* __restrict__ attractor, const float* __restrict__ exogd,
    const float* __restrict__ X0, const float* __restrict__ exogp,
    const void* __restrict__ housing, const void* __restrict__ genflux,
    float* __restrict__ ws) {
  const int wave = threadIdx.x >> 6;
  const int lane = threadIdx.x & 63;
  const int half = lane >> 5;
  const int n    = lane & 31;
  const int i    = blockIdx.x * 8 + wave * 2 + half;
  const bool nv  = (n < MDIM);
  float Uv = 0.f, asl = NEG_INF_F;
  if (nv) {
    Uv  = ws[OFF_U + n * ZDIM + i];
    asl = logf(fmaxf(attractor[n * ZDIM + i], EPS_F));
  }
  float acc = 0.f;
  for (int m = 0; m < MDIM; m++) {
    const float Xt  = X0[m * ZDIM + i] + exogp[m * ZDIM + i];
    const float sig = sigma[m];
    float dm = 0.f, dd = 0.f, dl = 0.f, om = 0.f, kn = 0.f;
    if (nv) {
      dm = demin[m * MDIM + n];
      dd = demax[m * MDIM + n] - dm;
      dl = delta[m * MDIM + n];
      om = omega[m * MDIM + n];
      kn = Kn[m * MDIM + n];
    }
    const float a = dm + dd * __expf(-dl * Uv);
    const bool valid = nv && (kn > 0.f);
    const float l = valid ? asl - sig * om * a * Uv : NEG_INF_F;
    float mx = l;
    #pragma unroll
    for (int off = 16; off >= 1; off >>= 1)
      mx = fmaxf(mx, __shfl_xor(mx, off));
    float e = valid ? __expf(l - mx) : 0.f;
    float se = e;
    #pragma unroll
    for (int off = 16; off >= 1; off >>= 1)
      se += __shfl_xor(se, off);
    const float S = (valid && se > 0.f) ? e / se : 1.0f;
    if (nv) acc = fmaf(a * S, Xt, acc);
  }
  if (nv) {
    const float Dv = exogd[n * ZDIM + i] + acc;
    ws[OFF_D + n * ZDIM + i]  = Dv;
    ws[OFF_XP + n * ZDIM + i] = loc_flag(housing, genflux, n) ? 0.f : Dv;
  }
}

__global__ __launch_bounds__(256) void k3_xpred(
    const float* __restrict__ t, const float* __restrict__ price,
    const float* __restrict__ h, const float* __restrict__ A_ni,
    const float* __restrict__ beta, const float* __restrict__ lamda,
    const void* __restrict__ housing, const void* __restrict__ genflux,
    float* __restrict__ ws) {
  const int n = blockIdx.x >> 5, ic = blockIdx.x & 31;
  if (!loc_flag(housing, genflux, n)) return;
  const int tj = threadIdx.x;
  const float bn = beta[n], ln = lamda[n];
  const float4 pr = ((const float4*)(price + n * ZDIM))[tj];
  const float4 hh = ((const float4*)(h     + n * ZDIM))[tj];
  const float4 aa = ((const float4*)(A_ni  + n * ZDIM))[tj];
  const float c0 = logf(fmaxf(aa.x, EPS_F)) - bn * (ln * (pr.x + hh.x));
  const float c1 = logf(fmaxf(aa.y, EPS_F)) - bn * (ln * (pr.y + hh.y));
  const float c2 = logf(fmaxf(aa.z, EPS_F)) - bn * (ln * (pr.z + hh.z));
  const float c3 = logf(fmaxf(aa.w, EPS_F)) - bn * (ln * (pr.w + hh.w));
  const float4* t4 = (const float4*)t;
  float x0 = 0.f, x1 = 0.f, x2 = 0.f, x3 = 0.f;
  for (int ii = 0; ii < 32; ii++) {
    const int i = ic * 32 + ii;
    const int row = n * ZDIM + i;
    const float mx = ws[OFF_RMAX + row];
    const float w  = ws[OFF_D + row] / ws[OFF_SEXP + row];
    float4 tv = t4[(size_t)row * (ZDIM / 4) + tj];
    x0 = fmaf(w, __expf(c0 - mx - bn * tv.x), x0);
    x1 = fmaf(w, __expf(c1 - mx - bn * tv.y), x1);
    x2 = fmaf(w, __expf(c2 - mx - bn * tv.z), x2);
    x3 = fmaf(w, __expf(c3 - mx - bn * tv.w), x3);
  }
  float* xp = ws + OFF_XP + n * ZDIM + tj * 4;
  atomicAdd(xp + 0, x0);
  atomicAdd(xp + 1, x1);
  atomicAdd(xp + 2, x2);
  atomicAdd(xp + 3, x3);
}

__global__ __launch_bounds__(1024) void k4_loss(
    const float* __restrict__ Xtg, const float* __restrict__ ws,
    float* __restrict__ out) {
  float s = 0.f;
  for (int e = threadIdx.x; e < MDIM * ZDIM; e += 1024) {
    float d = ws[OFF_XP + e] - Xtg[e];
    s = fmaf(d, d, s);
  }
  #pragma unroll
  for (int off = 32; off >= 1; off >>= 1) s += __shfl_xor(s, off);
  __shared__ float red[16];
  const int w = threadIdx.x >> 6, lane = threadIdx.x & 63;
  if (lane == 0) red[w] = s;
  __syncthreads();
  if (threadIdx.x == 0) {
    float tot = 0.f;
    #pragma unroll
    for (int k = 0; k < 16; k++) tot += red[k];
    *out = tot * (1.0f / (MDIM * ZDIM));
  }
}

extern "C" void kernel_launch(void* const* d_in, const int* in_sizes, int n_in,
                              void* d_out, int out_size, void* d_ws, size_t ws_size,
                              hipStream_t stream) {
  (void)in_sizes; (void)n_in; (void)out_size; (void)ws_size;
  const float* h       = (const float*)d_in[0];
  const float* price   = (const float*)d_in[1];
  const float* t       = (const float*)d_in[2];
  const float* demin   = (const float*)d_in[3];
  const float* demax   = (const float*)d_in[4];
  const float* delta   = (const float*)d_in[5];
  const float* omega   = (const float*)d_in[6];
  const float* sigma   = (const float*)d_in[7];
  const float* Kn      = (const float*)d_in[8];
  const float* attract = (const float*)d_in[9];
  const float* beta    = (const float*)d_in[10];
  const float* lamda   = (const float*)d_in[11];
  const float* A_ni    = (const float*)d_in[12];
  const float* exogd   = (const float*)d_in[13];
  const float* exogp   = (const float*)d_in[14];
  const float* X0      = (const float*)d_in[15];
  const float* Xtg     = (const float*)d_in[16];
  const void*  housing = d_in[17];
  const void*  genflux = d_in[18];
  float* ws  = (float*)d_ws;
  float* out = (float*)d_out;

  void* args[] = {
    (void*)&t, (void*)&price, (void*)&h, (void*)&A_ni, (void*)&beta,
    (void*)&lamda, (void*)&demin, (void*)&demax, (void*)&delta, (void*)&omega,
    (void*)&sigma, (void*)&Kn, (void*)&attract, (void*)&exogd, (void*)&X0,
    (void*)&exogp, (void*)&Xtg, (void*)&housing, (void*)&genflux,
    (void*)&ws, (void*)&out
  };
  hipError_t err = hipLaunchCooperativeKernel((const void*)fused, dim3(NBLK),
                                              dim3(NTHR), args, 0, stream);
  if (err != hipSuccess) {
    // fallback: verified 4-kernel pipeline (same math, same ws offsets)
    k1_rows<<<MDIM * 256, 256, 0, stream>>>(t, price, h, A_ni, beta, lamda,
                                            housing, genflux, ws);
    k2_demand<<<128, 256, 0, stream>>>(demin, demax, delta, omega, sigma, Kn,
                                       attract, exogd, X0, exogp,
                                       housing, genflux, ws);
    k3_xpred<<<MDIM * 32, 256, 0, stream>>>(t, price, h, A_ni, beta, lamda,
                                            housing, genflux, ws);
    k4_loss<<<1, 1024, 0, stream>>>(Xtg, ws, out);
  }
}

// Round 8
// 237.835 us; speedup vs baseline: 3.4313x; 3.4313x over previous
//
#include <hip/hip_runtime.h>
#include <hip/hip_bf16.h>
#include <math.h>

#define MDIM 24
#define ZDIM 1024
#define NEG_INF_F -1e30f
#define EPS_F 1e-12f

// ws layout (float offsets)
enum {
  OFF_U    = 0,            // U_ni            [24][1024]
  OFF_RMAX = 24576,        // loc-logit max   [24][1024]
  OFF_SEXP = 49152,        // loc sumexp      [24][1024]
  OFF_W    = 73728,        // D/sumexp (loc)  [24][1024]
  OFF_XP   = 98304         // X_pred          [24][1024]
};

// ---- mask handling: bool masks may arrive as packed bytes or 32-bit words.
__device__ __forceinline__ bool masks_are_bytes(const void* hm, const void* gm) {
  const unsigned int* hw = (const unsigned int*)hm;
  const unsigned int* gw = (const unsigned int*)gm;
  bool b = false;
  #pragma unroll
  for (int k = 0; k < 6; k++) {   // first 24 bytes of each — safe in all layouts
    unsigned int a = hw[k], c = gw[k];
    if (a != 0u && a != 1u && a != 0x3F800000u) b = true;
    if (c != 0u && c != 1u && c != 0x3F800000u) b = true;
  }
  return b;
}
__device__ __forceinline__ bool loc_flag(const void* hm, const void* gm, int n) {
  bool bytes = masks_are_bytes(hm, gm);
  bool hv = bytes ? (((const unsigned char*)hm)[n] != 0)
                  : (((const unsigned int*)hm)[n] != 0u);
  bool gv = bytes ? (((const unsigned char*)gm)[n] != 0)
                  : (((const unsigned int*)gm)[n] != 0u);
  return gv && !hv;
}

// K1: per-(n,i) row — location-softmax stats + composite disutility U_ni.
// 16 rows/block (4 rows/wave, processed in pairs for 8-deep global-load ILP).
__global__ __launch_bounds__(256) void k1_rows(
    const float* __restrict__ t, const float* __restrict__ price,
    const float* __restrict__ h, const float* __restrict__ A_ni,
    const float* __restrict__ beta, const float* __restrict__ lamda,
    const void* __restrict__ housing, const void* __restrict__ genflux,
    float* __restrict__ ws) {
  const int n  = blockIdx.x >> 6;            // 64 blocks per sector
  const int i0 = (blockIdx.x & 63) * 16;
  const float bn = beta[n], ln = lamda[n];
  const bool lf = loc_flag(housing, genflux, n);
  if (!lf) {
    // Pr = eye  =>  U = lamda*(price+h) + t[i,i]; no staging needed
    if (threadIdx.x < 16) {
      const int row = n * ZDIM + i0 + threadIdx.x;
      ws[OFF_U + row] = ln * (price[row] + h[row])
                        + t[(size_t)row * ZDIM + (i0 + threadIdx.x)];
    }
    return;
  }
  __shared__ float pc_s[ZDIM];               // lamda*(price+h)
  __shared__ float cc_s[ZDIM];               // slog(A) - beta*pc
  for (int j = threadIdx.x; j < ZDIM; j += 256) {
    const float pc = ln * (price[n * ZDIM + j] + h[n * ZDIM + j]);
    const float sa = logf(fmaxf(A_ni[n * ZDIM + j], EPS_F));
    pc_s[j] = pc;
    cc_s[j] = sa - bn * pc;
  }
  __syncthreads();
  const int wave = threadIdx.x >> 6, lane = threadIdx.x & 63;
  const float4* pc4 = (const float4*)pc_s;
  const float4* cc4 = (const float4*)cc_s;

  auto do_row = [&](int row, float4 t0, float4 t1, float4 t2, float4 t3) {
    float lg[16], uv[16];
    float mx = -INFINITY;
    const float4 tt[4] = {t0, t1, t2, t3};
    #pragma unroll
    for (int k = 0; k < 4; k++) {
      const int f = lane + 64 * k;
      const float4 tv = tt[k];
      const float4 pv = pc4[f];
      const float4 cv = cc4[f];
      uv[4*k+0] = pv.x + tv.x;  lg[4*k+0] = cv.x - bn * tv.x;
      uv[4*k+1] = pv.y + tv.y;  lg[4*k+1] = cv.y - bn * tv.y;
      uv[4*k+2] = pv.z + tv.z;  lg[4*k+2] = cv.z - bn * tv.z;
      uv[4*k+3] = pv.w + tv.w;  lg[4*k+3] = cv.w - bn * tv.w;
      mx = fmaxf(mx, fmaxf(fmaxf(lg[4*k], lg[4*k+1]), fmaxf(lg[4*k+2], lg[4*k+3])));
    }
    #pragma unroll
    for (int off = 32; off >= 1; off >>= 1)
      mx = fmaxf(mx, __shfl_xor(mx, off));
    float se = 0.f, su = 0.f;
    #pragma unroll
    for (int k = 0; k < 16; k++) {
      const float e = __expf(lg[k] - mx);
      se += e;
      su = fmaf(e, uv[k], su);
    }
    #pragma unroll
    for (int off = 32; off >= 1; off >>= 1) {
      se += __shfl_xor(se, off);
      su += __shfl_xor(su, off);
    }
    if (lane == 0) {
      ws[OFF_U + row]    = su / se;
      ws[OFF_RMAX + row] = mx;
      ws[OFF_SEXP + row] = se;
    }
  };

  #pragma unroll
  for (int p = 0; p < 2; p++) {               // 2 pairs of rows per wave
    const int rA = n * ZDIM + i0 + wave * 4 + p * 2;
    const int rB = rA + 1;
    const float4* tA = (const float4*)(t + (size_t)rA * ZDIM);
    const float4* tB = (const float4*)(t + (size_t)rB * ZDIM);
    // issue all 8 loads before any dependent compute
    const float4 a0 = tA[lane], a1 = tA[lane + 64],
                 a2 = tA[lane + 128], a3 = tA[lane + 192];
    const float4 b0 = tB[lane], b1 = tB[lane + 64],
                 b2 = tB[lane + 128], b3 = tB[lane + 192];
    do_row(rA, a0, a1, a2, a3);
    do_row(rB, b0, b1, b2, b3);
  }
}

// K2: substitution softmax over n + total demand.
// 32-lane half-wave per zone i; lane n<24 owns sector n (verified layout).
// Writes W = D/sumexp for loc sectors (k3's weight) and XP for eye sectors.
__global__ __launch_bounds__(256) void k2_demand(
    const float* __restrict__ demin, const float* __restrict__ demax,
    const float* __restrict__ delta, const float* __restrict__ omega,
    const float* __restrict__ sigma, const float* __restrict__ Kn,
    const float* __restrict__ attractor, const float* __restrict__ exogd,
    const float* __restrict__ X0, const float* __restrict__ exogp,
    const void* __restrict__ housing, const void* __restrict__ genflux,
    float* __restrict__ ws) {
  const int wave = threadIdx.x >> 6;
  const int lane = threadIdx.x & 63;
  const int half = lane >> 5;
  const int n    = lane & 31;
  const int i    = blockIdx.x * 8 + wave * 2 + half;   // 128 blocks -> 0..1023
  const bool nv  = (n < MDIM);
  float Uv = 0.f, asl = NEG_INF_F;
  if (nv) {
    Uv  = ws[OFF_U + n * ZDIM + i];
    asl = logf(fmaxf(attractor[n * ZDIM + i], EPS_F));
  }
  float acc = 0.f;
  for (int m = 0; m < MDIM; m++) {
    const float Xt  = X0[m * ZDIM + i] + exogp[m * ZDIM + i];
    const float sig = sigma[m];
    float dm = 0.f, dd = 0.f, dl = 0.f, om = 0.f, kn = 0.f;
    if (nv) {
      dm = demin[m * MDIM + n];
      dd = demax[m * MDIM + n] - dm;
      dl = delta[m * MDIM + n];
      om = omega[m * MDIM + n];
      kn = Kn[m * MDIM + n];
    }
    const float a = dm + dd * __expf(-dl * Uv);
    const bool valid = nv && (kn > 0.f);
    const float l = valid ? asl - sig * om * a * Uv : NEG_INF_F;
    float mx = l;
    #pragma unroll
    for (int off = 16; off >= 1; off >>= 1)
      mx = fmaxf(mx, __shfl_xor(mx, off));    // stays within 32-lane half
    const float e = valid ? __expf(l - mx) : 0.f;
    float se = e;
    #pragma unroll
    for (int off = 16; off >= 1; off >>= 1)
      se += __shfl_xor(se, off);
    const float S = (valid && se > 0.f) ? e / se : 1.0f;
    if (nv) acc = fmaf(a * S, Xt, acc);
  }
  if (nv) {
    const float Dv = exogd[n * ZDIM + i] + acc;
    if (loc_flag(housing, genflux, n)) {
      ws[OFF_W  + n * ZDIM + i] = Dv / ws[OFF_SEXP + n * ZDIM + i];
      ws[OFF_XP + n * ZDIM + i] = 0.f;        // k3 accumulates from 0
    } else {
      ws[OFF_XP + n * ZDIM + i] = Dv;         // eye-sector X_pred = D
    }
  }
}

// K3: X_pred[n,j] += sum_i W_i * exp(c_j - max_i - beta*t[n,i,j])
// grid = (n, 64 i-chunks of 16); loc sectors only; prefetched second t-pass.
__global__ __launch_bounds__(256) void k3_xpred(
    const float* __restrict__ t, const float* __restrict__ price,
    const float* __restrict__ h, const float* __restrict__ A_ni,
    const float* __restrict__ beta, const float* __restrict__ lamda,
    const void* __restrict__ housing, const void* __restrict__ genflux,
    float* __restrict__ ws) {
  const int n = blockIdx.x >> 6, ic = blockIdx.x & 63;
  if (!loc_flag(housing, genflux, n)) return;
  const int tj = threadIdx.x;                       // float4 index over j
  const float bn = beta[n], ln = lamda[n];
  const float4 pr = ((const float4*)(price + n * ZDIM))[tj];
  const float4 hh = ((const float4*)(h     + n * ZDIM))[tj];
  const float4 aa = ((const float4*)(A_ni  + n * ZDIM))[tj];
  const float c0 = logf(fmaxf(aa.x, EPS_F)) - bn * (ln * (pr.x + hh.x));
  const float c1 = logf(fmaxf(aa.y, EPS_F)) - bn * (ln * (pr.y + hh.y));
  const float c2 = logf(fmaxf(aa.z, EPS_F)) - bn * (ln * (pr.z + hh.z));
  const float c3 = logf(fmaxf(aa.w, EPS_F)) - bn * (ln * (pr.w + hh.w));
  const float4* t4 = (const float4*)t;
  int row = n * ZDIM + ic * 16;
  // prefetch iteration 0
  float  mx_c = ws[OFF_RMAX + row];
  float  w_c  = ws[OFF_W + row];
  float4 tv_c = t4[(size_t)row * (ZDIM / 4) + tj];
  float x0 = 0.f, x1 = 0.f, x2 = 0.f, x3 = 0.f;
  for (int ii = 0; ii < 16; ii++) {
    float mx_n = 0.f, w_n = 0.f;
    float4 tv_n = tv_c;
    if (ii < 15) {                                   // prefetch next row
      mx_n = ws[OFF_RMAX + row + 1];
      w_n  = ws[OFF_W + row + 1];
      tv_n = t4[(size_t)(row + 1) * (ZDIM / 4) + tj];
    }
    x0 = fmaf(w_c, __expf(c0 - mx_c - bn * tv_c.x), x0);
    x1 = fmaf(w_c, __expf(c1 - mx_c - bn * tv_c.y), x1);
    x2 = fmaf(w_c, __expf(c2 - mx_c - bn * tv_c.z), x2);
    x3 = fmaf(w_c, __expf(c3 - mx_c - bn * tv_c.w), x3);
    mx_c = mx_n; w_c = w_n; tv_c = tv_n; row++;
  }
  float* xp = ws + OFF_XP + n * ZDIM + tj * 4;
  atomicAdd(xp + 0, x0);
  atomicAdd(xp + 1, x1);
  atomicAdd(xp + 2, x2);
  atomicAdd(xp + 3, x3);
}

// K4: loss = mean((X_pred - X_target)^2); out zeroed by memsetAsync.
__global__ __launch_bounds__(256) void k4_loss(
    const float* __restrict__ Xtg, const float* __restrict__ ws,
    float* __restrict__ out) {
  float s = 0.f;
  for (int e = blockIdx.x * 256 + threadIdx.x; e < MDIM * ZDIM; e += 48 * 256) {
    const float d = ws[OFF_XP + e] - Xtg[e];
    s = fmaf(d, d, s);
  }
  #pragma unroll
  for (int off = 32; off >= 1; off >>= 1) s += __shfl_xor(s, off);
  __shared__ float red[4];
  const int w = threadIdx.x >> 6, lane = threadIdx.x & 63;
  if (lane == 0) red[w] = s;
  __syncthreads();
  if (threadIdx.x == 0)
    atomicAdd(out, (red[0] + red[1] + red[2] + red[3]) * (1.0f / (MDIM * ZDIM)));
}

extern "C" void kernel_launch(void* const* d_in, const int* in_sizes, int n_in,
                              void* d_out, int out_size, void* d_ws, size_t ws_size,
                              hipStream_t stream) {
  (void)in_sizes; (void)n_in; (void)out_size; (void)ws_size;
  const float* h       = (const float*)d_in[0];
  const float* price   = (const float*)d_in[1];
  const float* t       = (const float*)d_in[2];
  const float* demin   = (const float*)d_in[3];
  const float* demax   = (const float*)d_in[4];
  const float* delta   = (const float*)d_in[5];
  const float* omega   = (const float*)d_in[6];
  const float* sigma   = (const float*)d_in[7];
  const float* Kn      = (const float*)d_in[8];
  const float* attract = (const float*)d_in[9];
  const float* beta    = (const float*)d_in[10];
  const float* lamda   = (const float*)d_in[11];
  const float* A_ni    = (const float*)d_in[12];
  const float* exogd   = (const float*)d_in[13];
  const float* exogp   = (const float*)d_in[14];
  const float* X0      = (const float*)d_in[15];
  const float* Xtg     = (const float*)d_in[16];
  const void*  housing = d_in[17];
  const void*  genflux = d_in[18];
  float* ws  = (float*)d_ws;
  float* out = (float*)d_out;

  k1_rows<<<MDIM * 64, 256, 0, stream>>>(t, price, h, A_ni, beta, lamda,
                                         housing, genflux, ws);
  k2_demand<<<128, 256, 0, stream>>>(demin, demax, delta, omega, sigma, Kn,
                                     attract, exogd, X0, exogp,
                                     housing, genflux, ws);
  k3_xpred<<<MDIM * 64, 256, 0, stream>>>(t, price, h, A_ni, beta, lamda,
                                          housing, genflux, ws);
  hipMemsetAsync(out, 0, sizeof(float), stream);
  k4_loss<<<48, 256, 0, stream>>>(Xtg, ws, out);
}